// Round 2
// baseline (428.281 us; speedup 1.0000x reference)
//
#include <hip/hip_runtime.h>

// Problem constants (fixed by setup_inputs)
#define BB 16
#define CC 128
#define DD 3
#define NN 4096
#define KK 1024   // NN / topk, topk = 4

// ---------------------------------------------------------------------------
// K1: per-(b,d,n) mean over c, in fp64.  mean = sum * (1/128)  (exact pow2)
// tid = (b*3+d)*4096 + n ; consecutive threads -> consecutive n (coalesced)
// ---------------------------------------------------------------------------
__global__ void k_means(const float* __restrict__ fx, const float* __restrict__ fy,
                        double* __restrict__ mx, double* __restrict__ my) {
    int tid = blockIdx.x * blockDim.x + threadIdx.x;   // [0, BB*DD*NN)
    int n  = tid & (NN - 1);
    int bd = tid >> 12;            // b*3 + d
    int b  = bd / 3;
    int d  = bd - 3 * b;
    const size_t cstride = (size_t)DD * NN;
    size_t base = (size_t)b * CC * cstride + (size_t)d * NN + n;
    double sx = 0.0, sy = 0.0;
    #pragma unroll 4
    for (int c = 0; c < CC; ++c) {
        size_t off = base + (size_t)c * cstride;
        sx += (double)fx[off];
        sy += (double)fy[off];
    }
    mx[tid] = sx * (1.0 / 128.0);
    my[tid] = sy * (1.0 / 128.0);
}

// ---------------------------------------------------------------------------
// K2: per-(b,n) score s = sum_c (fx_c . xhat)(fy_c . yhat), all fp64.
// xhat = mean / (||mean|| + 1e-6)  (division, matching reference formula)
// ---------------------------------------------------------------------------
__global__ void k_score(const float* __restrict__ fx, const float* __restrict__ fy,
                        const double* __restrict__ mx, const double* __restrict__ my,
                        double* __restrict__ s) {
    int tid = blockIdx.x * blockDim.x + threadIdx.x;   // [0, BB*NN)
    int n = tid & (NN - 1);
    int b = tid >> 12;

    double mx0 = mx[(b*3 + 0) * NN + n];
    double mx1 = mx[(b*3 + 1) * NN + n];
    double mx2 = mx[(b*3 + 2) * NN + n];
    double my0 = my[(b*3 + 0) * NN + n];
    double my1 = my[(b*3 + 1) * NN + n];
    double my2 = my[(b*3 + 2) * NN + n];

    double nx = sqrt(mx0*mx0 + mx1*mx1 + mx2*mx2) + 1e-6;
    double ny = sqrt(my0*my0 + my1*my1 + my2*my2) + 1e-6;
    double x0 = mx0 / nx, x1 = mx1 / nx, x2 = mx2 / nx;
    double y0 = my0 / ny, y1 = my1 / ny, y2 = my2 / ny;

    const size_t cstride = (size_t)DD * NN;
    size_t base = (size_t)b * CC * cstride + n;
    double acc = 0.0;
    #pragma unroll 4
    for (int c = 0; c < CC; ++c) {
        size_t o = base + (size_t)c * cstride;
        double px = (double)fx[o] * x0 + (double)fx[o + NN] * x1 + (double)fx[o + 2*NN] * x2;
        double py = (double)fy[o] * y0 + (double)fy[o + NN] * y1 + (double)fy[o + 2*NN] * y2;
        acc += px * py;
    }
    s[tid] = acc;
}

// ---------------------------------------------------------------------------
// K3: exact lax.top_k ordering via rank counting.
// rank[n] = #{ m : s[m] > s[n]  or  (s[m]==s[n] and m < n) }
// rank < KK  ->  idx[b][rank] = n   (descending value, stable by index)
// One block handles (b, 256-wide n chunk); full row staged in LDS (32 KB).
// ---------------------------------------------------------------------------
__global__ void k_topk(const double* __restrict__ s, int* __restrict__ idx) {
    __shared__ double row[NN];
    int b     = blockIdx.x >> 4;       // 16 chunks per batch
    int chunk = blockIdx.x & 15;
    for (int i = threadIdx.x; i < NN; i += 256)
        row[i] = s[(size_t)b * NN + i];
    __syncthreads();

    int n = chunk * 256 + threadIdx.x;
    double v = row[n];
    int cnt = 0;
    #pragma unroll 8
    for (int m = 0; m < NN; ++m) {
        double u = row[m];                      // broadcast read, conflict-free
        cnt += (u > v) || (u == v && m < n);
    }
    if (cnt < KK)
        idx[b * KK + cnt] = n;
}

// ---------------------------------------------------------------------------
// K4: gather.  out = [fx_sel (b,c,d,KK) | fy_sel (b,c,d,KK)] flat.
// grid.x = row = b*384 + c*3 + d ; grid.y selects fx/fy half.
// Writes coalesced; gather reads LLC-warm.
// ---------------------------------------------------------------------------
__global__ void k_gather(const float* __restrict__ fx, const float* __restrict__ fy,
                         const int* __restrict__ idx, float* __restrict__ out) {
    int row = blockIdx.x;                  // [0, BB*CC*DD)
    int b   = row / (CC * DD);
    const float* src = blockIdx.y ? fy : fx;
    float* dst = out + (size_t)blockIdx.y * ((size_t)BB * CC * DD * KK);
    const int* id = idx + b * KK;
    size_t sbase = (size_t)row * NN;
    size_t dbase = (size_t)row * KK;
    #pragma unroll
    for (int j = threadIdx.x; j < KK; j += 256)
        dst[dbase + j] = src[sbase + id[j]];
}

extern "C" void kernel_launch(void* const* d_in, const int* in_sizes, int n_in,
                              void* d_out, int out_size, void* d_ws, size_t ws_size,
                              hipStream_t stream) {
    const float* fx = (const float*)d_in[0];
    const float* fy = (const float*)d_in[1];
    float* out = (float*)d_out;

    // workspace layout (fp64 means, fp64 scores, int idx) -- ~3.73 MB total
    double* mx = (double*)d_ws;                  // BB*DD*NN
    double* my = mx + (size_t)BB * DD * NN;      // BB*DD*NN
    double* s  = my + (size_t)BB * DD * NN;      // BB*NN
    int*    idx = (int*)(s + (size_t)BB * NN);   // BB*KK

    k_means <<<(BB * DD * NN) / 256, 256, 0, stream>>>(fx, fy, mx, my);
    k_score <<<(BB * NN) / 256,      256, 0, stream>>>(fx, fy, mx, my, s);
    k_topk  <<<BB * 16,              256, 0, stream>>>(s, idx);
    k_gather<<<dim3(BB * CC * DD, 2),256, 0, stream>>>(fx, fy, idx, out);
}

// Round 3
// 353.711 us; speedup vs baseline: 1.2108x; 1.2108x over previous
//
#include <hip/hip_runtime.h>

// Problem constants (fixed by setup_inputs)
#define BB 16
#define CC 128
#define DD 3
#define NN 4096
#define KK 1024           // NN / topk, topk = 4
#define BN (BB * NN)      // 65536

// ---------------------------------------------------------------------------
// A: fused moments + score, ONE pass over fx/fy (402 MB instead of 804 MB).
//   s[b,n] = xhat . M . yhat,  M[d][e] = sum_c fx[c,d]*fy[c,e]  (fp64 exact:
//   fp32*fp32 fits in 53-bit mantissa), xhat = mean/(||mean||+1e-6).
// Block = 256 threads covering 128 consecutive n x 2 c-halves; LDS reduce.
// Emits monotonic u64 key (descending s == descending u) and zeroes cnt.
// ---------------------------------------------------------------------------
__global__ __launch_bounds__(256) void k_moments(
        const float* __restrict__ fx, const float* __restrict__ fy,
        unsigned long long* __restrict__ skey, int* __restrict__ cnt) {
    __shared__ double lds[15][128];   // [moment][n-slot], 2-way bank alias only
    int t = threadIdx.x;
    int p = t & 127;                  // n-slot within block
    int half = t >> 7;                // which 64-c half
    int gpi = blockIdx.x * 128 + p;   // global (b,n) index
    int b = gpi >> 12;
    int n = gpi & (NN - 1);

    const size_t cstride = (size_t)DD * NN;                       // 12288
    size_t base = ((size_t)b * CC + (size_t)half * 64) * cstride + n;

    double sx0=0,sx1=0,sx2=0, sy0=0,sy1=0,sy2=0;
    double m00=0,m01=0,m02=0, m10=0,m11=0,m12=0, m20=0,m21=0,m22=0;
    #pragma unroll 4
    for (int c = 0; c < 64; ++c) {
        size_t o = base + (size_t)c * cstride;
        double x0 = (double)fx[o], x1 = (double)fx[o + NN], x2 = (double)fx[o + 2*NN];
        double y0 = (double)fy[o], y1 = (double)fy[o + NN], y2 = (double)fy[o + 2*NN];
        sx0 += x0; sx1 += x1; sx2 += x2;
        sy0 += y0; sy1 += y1; sy2 += y2;
        m00 += x0*y0; m01 += x0*y1; m02 += x0*y2;
        m10 += x1*y0; m11 += x1*y1; m12 += x1*y2;
        m20 += x2*y0; m21 += x2*y1; m22 += x2*y2;
    }
    if (half) {
        lds[0][p]=sx0;  lds[1][p]=sx1;  lds[2][p]=sx2;
        lds[3][p]=sy0;  lds[4][p]=sy1;  lds[5][p]=sy2;
        lds[6][p]=m00;  lds[7][p]=m01;  lds[8][p]=m02;
        lds[9][p]=m10;  lds[10][p]=m11; lds[11][p]=m12;
        lds[12][p]=m20; lds[13][p]=m21; lds[14][p]=m22;
    }
    __syncthreads();
    if (!half) {
        sx0+=lds[0][p];  sx1+=lds[1][p];  sx2+=lds[2][p];
        sy0+=lds[3][p];  sy1+=lds[4][p];  sy2+=lds[5][p];
        m00+=lds[6][p];  m01+=lds[7][p];  m02+=lds[8][p];
        m10+=lds[9][p];  m11+=lds[10][p]; m12+=lds[11][p];
        m20+=lds[12][p]; m21+=lds[13][p]; m22+=lds[14][p];

        double mx0 = sx0*(1.0/128.0), mx1 = sx1*(1.0/128.0), mx2 = sx2*(1.0/128.0);
        double my0 = sy0*(1.0/128.0), my1 = sy1*(1.0/128.0), my2 = sy2*(1.0/128.0);
        double nx = sqrt(mx0*mx0 + mx1*mx1 + mx2*mx2) + 1e-6;
        double ny = sqrt(my0*my0 + my1*my1 + my2*my2) + 1e-6;
        double x0 = mx0/nx, x1 = mx1/nx, x2 = mx2/nx;
        double y0 = my0/ny, y1 = my1/ny, y2 = my2/ny;

        double s = x0*(y0*m00 + y1*m01 + y2*m02)
                 + x1*(y0*m10 + y1*m11 + y2*m12)
                 + x2*(y0*m20 + y1*m21 + y2*m22);

        // monotonic map: descending double order == descending u64 order
        long long bits = __double_as_longlong(s);
        unsigned long long u = (bits < 0)
            ? ~(unsigned long long)bits
            : ((unsigned long long)bits | 0x8000000000000000ULL);
        skey[gpi] = u;
        cnt[gpi] = 0;          // harness poisons ws each launch; re-init here
    }
}

// ---------------------------------------------------------------------------
// B: partial rank count.  rank[n] = #{ m : key[m]>key[n] or (== and m<n) }
// grid = 16 b x 16 n-chunks x 4 m-chunks = 1024 blocks (4x occupancy, 4x
// shallower serial loop than before).  Integer u64 compares, exact.
// ---------------------------------------------------------------------------
__global__ __launch_bounds__(256) void k_count(
        const unsigned long long* __restrict__ skey, int* __restrict__ cnt) {
    __shared__ unsigned long long tile[1024];
    int b      = blockIdx.x >> 6;
    int nchunk = (blockIdx.x >> 2) & 15;
    int mchunk = blockIdx.x & 3;
    const unsigned long long* srow = skey + b * NN;
    int m0 = mchunk * 1024;
    for (int i = threadIdx.x; i < 1024; i += 256)
        tile[i] = srow[m0 + i];
    __syncthreads();

    int n = nchunk * 256 + threadIdx.x;
    unsigned long long un = srow[n];
    int c = 0;
    #pragma unroll 8
    for (int m = 0; m < 1024; ++m) {
        unsigned long long um = tile[m];        // broadcast read
        c += (um > un) || (um == un && (m0 + m) < n);
    }
    atomicAdd(&cnt[b * NN + n], c);
}

// ---------------------------------------------------------------------------
// C: scatter ranks -> indices (lax.top_k order: descending, stable by index)
// ---------------------------------------------------------------------------
__global__ void k_scatter(const int* __restrict__ cnt, int* __restrict__ idx) {
    int b = blockIdx.x;
    for (int i = threadIdx.x; i < NN; i += 256) {
        int r = cnt[b * NN + i];
        if (r < KK) idx[b * KK + r] = i;
    }
}

// ---------------------------------------------------------------------------
// D: gather.  out = [fx_sel (b,c,d,KK) | fy_sel (b,c,d,KK)] flat.
// Writes coalesced; gather reads partially L2/L3-warm.
// ---------------------------------------------------------------------------
__global__ void k_gather(const float* __restrict__ fx, const float* __restrict__ fy,
                         const int* __restrict__ idx, float* __restrict__ out) {
    int row = blockIdx.x;                  // [0, BB*CC*DD)
    int b   = row / (CC * DD);
    const float* src = blockIdx.y ? fy : fx;
    float* dst = out + (size_t)blockIdx.y * ((size_t)BB * CC * DD * KK);
    const int* id = idx + b * KK;
    size_t sbase = (size_t)row * NN;
    size_t dbase = (size_t)row * KK;
    #pragma unroll
    for (int j = threadIdx.x; j < KK; j += 256)
        dst[dbase + j] = src[sbase + id[j]];
}

extern "C" void kernel_launch(void* const* d_in, const int* in_sizes, int n_in,
                              void* d_out, int out_size, void* d_ws, size_t ws_size,
                              hipStream_t stream) {
    const float* fx = (const float*)d_in[0];
    const float* fy = (const float*)d_in[1];
    float* out = (float*)d_out;

    // ws layout: u64 skey[BN] (512KB) | int cnt[BN] (256KB) | int idx[BB*KK] (64KB)
    unsigned long long* skey = (unsigned long long*)d_ws;
    int* cnt = (int*)(skey + BN);
    int* idx = cnt + BN;

    k_moments<<<BN / 128, 256, 0, stream>>>(fx, fy, skey, cnt);
    k_count  <<<BB * 16 * 4, 256, 0, stream>>>(skey, cnt);
    k_scatter<<<BB, 256, 0, stream>>>(cnt, idx);
    k_gather <<<dim3(BB * CC * DD, 2), 256, 0, stream>>>(fx, fy, idx, out);
}

// Round 5
// 328.765 us; speedup vs baseline: 1.3027x; 1.0759x over previous
//
#include <hip/hip_runtime.h>

// Problem constants (fixed by setup_inputs)
#define BB 16
#define CC 128
#define DD 3
#define NN 4096
#define KK 1024           // NN / topk, topk = 4
#define BN (BB * NN)      // 65536
#define CH 512            // m-chunk length in k_count

// ---------------------------------------------------------------------------
// A: fused moments + score, ONE pass over fx/fy.
//   s[b,n] = xhat . M . yhat,  M[d][e] = sum_c fx[c,d]*fy[c,e]  (fp64 exact:
//   fp32*fp32 products are exact in fp64), xhat = mean/(||mean||+1e-6).
// Block = 256 threads = 64 consecutive n x 4 c-quarters; LDS 3-way reduce.
// 1024 blocks -> 16 waves/CU (2x the old 2-half version) for latency hiding.
// Emits monotonic u64 key (descending s == descending u) and zeroes cnt.
// ---------------------------------------------------------------------------
__global__ __launch_bounds__(256) void k_moments(
        const float* __restrict__ fx, const float* __restrict__ fy,
        unsigned long long* __restrict__ skey, int* __restrict__ cnt) {
    __shared__ double lds[3][15][64];   // [quarter-1][moment][n-slot] = 22.5 KB
    int t = threadIdx.x;
    int p = t & 63;                   // n-slot within block
    int q = t >> 6;                   // c-quarter 0..3
    int gpi = blockIdx.x * 64 + p;    // global (b,n) index
    int b = gpi >> 12;
    int n = gpi & (NN - 1);

    const size_t cstride = (size_t)DD * NN;                       // 12288
    size_t base = ((size_t)b * CC + (size_t)q * 32) * cstride + n;

    double sx0=0,sx1=0,sx2=0, sy0=0,sy1=0,sy2=0;
    double m00=0,m01=0,m02=0, m10=0,m11=0,m12=0, m20=0,m21=0,m22=0;
    #pragma unroll 4
    for (int c = 0; c < 32; ++c) {
        size_t o = base + (size_t)c * cstride;
        double x0 = (double)fx[o], x1 = (double)fx[o + NN], x2 = (double)fx[o + 2*NN];
        double y0 = (double)fy[o], y1 = (double)fy[o + NN], y2 = (double)fy[o + 2*NN];
        sx0 += x0; sx1 += x1; sx2 += x2;
        sy0 += y0; sy1 += y1; sy2 += y2;
        m00 += x0*y0; m01 += x0*y1; m02 += x0*y2;
        m10 += x1*y0; m11 += x1*y1; m12 += x1*y2;
        m20 += x2*y0; m21 += x2*y1; m22 += x2*y2;
    }
    if (q) {
        int qq = q - 1;
        lds[qq][0][p]=sx0;  lds[qq][1][p]=sx1;  lds[qq][2][p]=sx2;
        lds[qq][3][p]=sy0;  lds[qq][4][p]=sy1;  lds[qq][5][p]=sy2;
        lds[qq][6][p]=m00;  lds[qq][7][p]=m01;  lds[qq][8][p]=m02;
        lds[qq][9][p]=m10;  lds[qq][10][p]=m11; lds[qq][11][p]=m12;
        lds[qq][12][p]=m20; lds[qq][13][p]=m21; lds[qq][14][p]=m22;
    }
    __syncthreads();
    if (!q) {
        #pragma unroll
        for (int r = 0; r < 3; ++r) {
            sx0+=lds[r][0][p];  sx1+=lds[r][1][p];  sx2+=lds[r][2][p];
            sy0+=lds[r][3][p];  sy1+=lds[r][4][p];  sy2+=lds[r][5][p];
            m00+=lds[r][6][p];  m01+=lds[r][7][p];  m02+=lds[r][8][p];
            m10+=lds[r][9][p];  m11+=lds[r][10][p]; m12+=lds[r][11][p];
            m20+=lds[r][12][p]; m21+=lds[r][13][p]; m22+=lds[r][14][p];
        }
        double mx0 = sx0*(1.0/128.0), mx1 = sx1*(1.0/128.0), mx2 = sx2*(1.0/128.0);
        double my0 = sy0*(1.0/128.0), my1 = sy1*(1.0/128.0), my2 = sy2*(1.0/128.0);
        double nx = sqrt(mx0*mx0 + mx1*mx1 + mx2*mx2) + 1e-6;
        double ny = sqrt(my0*my0 + my1*my1 + my2*my2) + 1e-6;
        double x0 = mx0/nx, x1 = mx1/nx, x2 = mx2/nx;
        double y0 = my0/ny, y1 = my1/ny, y2 = my2/ny;

        double s = x0*(y0*m00 + y1*m01 + y2*m02)
                 + x1*(y0*m10 + y1*m11 + y2*m12)
                 + x2*(y0*m20 + y1*m21 + y2*m22);

        // monotonic map: descending double order == descending u64 order
        long long bits = __double_as_longlong(s);
        unsigned long long u = (bits < 0)
            ? ~(unsigned long long)bits
            : ((unsigned long long)bits | 0x8000000000000000ULL);
        skey[gpi] = u;
        cnt[gpi] = 0;          // ws is poisoned each launch; re-init here
    }
}

// ---------------------------------------------------------------------------
// B: partial rank count.  rank[n] = #{ m : key[m]>key[n] or (== and m<n) }
// grid = 16 b x 16 n-chunks x 8 m-chunks = 2048 blocks -> 32 waves/CU.
// Tie term uses precomputed lim = n - m0:  (global m < n)  <=>  (m < lim).
// ---------------------------------------------------------------------------
__global__ __launch_bounds__(256) void k_count(
        const unsigned long long* __restrict__ skey, int* __restrict__ cnt) {
    __shared__ unsigned long long tile[CH];
    int b      = blockIdx.x >> 7;          // 16n x 8m = 128 blocks per batch
    int nchunk = (blockIdx.x >> 3) & 15;
    int mchunk = blockIdx.x & 7;
    const unsigned long long* srow = skey + b * NN;
    int m0 = mchunk * CH;
    for (int i = threadIdx.x; i < CH; i += 256)
        tile[i] = srow[m0 + i];
    __syncthreads();

    int n = nchunk * 256 + threadIdx.x;
    unsigned long long un = srow[n];
    int lim = n - m0;                      // m < lim  <=>  (m0+m) < n
    int c = 0;
    #pragma unroll 8
    for (int m = 0; m < CH; ++m) {
        unsigned long long um = tile[m];   // broadcast read, conflict-free
        c += (um > un);
        c += (um == un) & (m < lim);
    }
    atomicAdd(&cnt[b * NN + n], c);
}

// ---------------------------------------------------------------------------
// C: scatter ranks -> indices (lax.top_k order: descending, stable by index)
// ---------------------------------------------------------------------------
__global__ void k_scatter(const int* __restrict__ cnt, int* __restrict__ idx) {
    int b = blockIdx.x;
    for (int i = threadIdx.x; i < NN; i += 256) {
        int r = cnt[b * NN + i];
        if (r < KK) idx[b * KK + r] = i;
    }
}

// ---------------------------------------------------------------------------
// D: gather.  out = [fx_sel (b,c,d,KK) | fy_sel (b,c,d,KK)] flat.
// Writes coalesced; reads touch ~97% of each row's 128B lines (1024 of 4096
// cols) so the re-read is effectively a full second pass -- HBM floor.
// ---------------------------------------------------------------------------
__global__ void k_gather(const float* __restrict__ fx, const float* __restrict__ fy,
                         const int* __restrict__ idx, float* __restrict__ out) {
    int row = blockIdx.x;                  // [0, BB*CC*DD)
    int b   = row / (CC * DD);
    const float* src = blockIdx.y ? fy : fx;
    float* dst = out + (size_t)blockIdx.y * ((size_t)BB * CC * DD * KK);
    const int* id = idx + b * KK;
    size_t sbase = (size_t)row * NN;
    size_t dbase = (size_t)row * KK;
    #pragma unroll
    for (int j = threadIdx.x; j < KK; j += 256)
        dst[dbase + j] = src[sbase + id[j]];
}

extern "C" void kernel_launch(void* const* d_in, const int* in_sizes, int n_in,
                              void* d_out, int out_size, void* d_ws, size_t ws_size,
                              hipStream_t stream) {
    const float* fx = (const float*)d_in[0];
    const float* fy = (const float*)d_in[1];
    float* out = (float*)d_out;

    // ws layout: u64 skey[BN] (512KB) | int cnt[BN] (256KB) | int idx[BB*KK] (64KB)
    unsigned long long* skey = (unsigned long long*)d_ws;
    int* cnt = (int*)(skey + BN);
    int* idx = cnt + BN;

    k_moments<<<BN / 64, 256, 0, stream>>>(fx, fy, skey, cnt);
    k_count  <<<BB * 16 * 8, 256, 0, stream>>>(skey, cnt);
    k_scatter<<<BB, 256, 0, stream>>>(cnt, idx);
    k_gather <<<dim3(BB * CC * DD, 2), 256, 0, stream>>>(fx, fy, idx, out);
}